// Round 6
// baseline (433.539 us; speedup 1.0000x reference)
//
#include <hip/hip_runtime.h>

#define E_EDGES 160000
#define N_NODES 10000

// 24^(-0.5)
#define TEMP 0.20412414523193154f

typedef __fp16 half2_t __attribute__((ext_vector_type(2)));
typedef __fp16 half8_t __attribute__((ext_vector_type(8)));
typedef float f32x4 __attribute__((ext_vector_type(4)));

__device__ __forceinline__ unsigned enc_f32(float x) {
    unsigned b = __float_as_uint(x);
    return b ^ ((b & 0x80000000u) ? 0xFFFFFFFFu : 0x80000000u);
}
__device__ __forceinline__ float dec_f32(unsigned k) {
    unsigned b = (k & 0x80000000u) ? (k ^ 0x80000000u) : ~k;
    return __uint_as_float(b);
}
__device__ __forceinline__ half2_t u2h(unsigned u) {
    union { unsigned u; half2_t h; } c; c.u = u; return c.h;
}
__device__ __forceinline__ float fdot2(half2_t a, half2_t b, float c) {
#if __has_builtin(__builtin_amdgcn_fdot2)
    return __builtin_amdgcn_fdot2(a, b, c, false);
#else
    return fmaf((float)a.x, (float)b.x, fmaf((float)a.y, (float)b.y, c));
#endif
}
__device__ __forceinline__ half2_t pk(float a, float b) {
    return __builtin_amdgcn_cvt_pkrtz(a, b);
}

// Kernel 0: W2 fp32 -> f16, row-major [768][64].
__global__ __launch_bounds__(256)
void w2cvt_kernel(const float* __restrict__ W2, unsigned* __restrict__ w2h)
{
    int t = blockIdx.x * blockDim.x + threadIdx.x;   // t < 24576
    float a = W2[2*t], b = W2[2*t+1];
    union { half2_t h; unsigned u; } c;
    c.h.x = (__fp16)a;  c.h.y = (__fp16)b;
    w2h[t] = c.u;
}

// Kernel 1: rw = h @ W2^T + b2 via MFMA. Each wave: 16 edges (M=16), N=768, K=64.
// h computed inline (VALU), staged in LDS for A-fragments. Output f16.
__global__ __launch_bounds__(256)
void gemm_kernel(const float* __restrict__ efeat, const float* __restrict__ W1,
                 const float* __restrict__ b1, const __fp16* __restrict__ w2h,
                 const float* __restrict__ b2, __fp16* __restrict__ rw,
                 int ebase)
{
    __shared__ __fp16 h_lds[4][16][64];   // 8 KB
    const int lane = threadIdx.x & 63;
    const int wid  = threadIdx.x >> 6;
    const int em   = lane & 15;
    const int quad = lane >> 4;
    const int etile = (blockIdx.x * 4 + wid) * 16;   // local (within chunk)

    // ---- h[etile+em][j in quad*16 .. +16), f16 into LDS ----
    {
        const int eg = ebase + etile + em;
        float x[32];
        const float4* xv = (const float4*)(efeat + (size_t)eg * 32);
        #pragma unroll
        for (int i = 0; i < 8; ++i) {
            float4 t = xv[i];
            x[4*i+0] = t.x; x[4*i+1] = t.y; x[4*i+2] = t.z; x[4*i+3] = t.w;
        }
        const int jg = quad * 16;
        half8_t hv0, hv1;
        #pragma unroll
        for (int t = 0; t < 16; ++t) {
            const int j = jg + t;
            float a = b1[j];
            const float* __restrict__ w = W1 + j*32;
            #pragma unroll
            for (int i = 0; i < 32; ++i) a = fmaf(w[i], x[i], a);
            a = fmaxf(a, 0.0f);
            if (t < 8) hv0[t] = (__fp16)a; else hv1[t-8] = (__fp16)a;
        }
        *(half8_t*)&h_lds[wid][em][jg]     = hv0;
        *(half8_t*)&h_lds[wid][em][jg + 8] = hv1;
    }
    __syncthreads();

    // A-fragments: A[m=em][k=quad*8+j], two K-chunks
    half8_t a0 = *(half8_t*)&h_lds[wid][em][quad*8];
    half8_t a1 = *(half8_t*)&h_lds[wid][em][quad*8 + 32];

    #pragma unroll 1
    for (int nt = 0; nt < 48; ++nt) {
        const int nrow = nt*16 + em;                       // c' index (W2 row)
        const half8_t* bp = (const half8_t*)(w2h + (size_t)nrow*64 + quad*8);
        half8_t bv0 = bp[0];     // k 0..31 chunk: W2[nrow][quad*8 .. +8)
        half8_t bv1 = bp[4];     // k 32..63: +32 halves = 4 half8
        float bi = b2[nrow];
        f32x4 acc = {bi, bi, bi, bi};
        acc = __builtin_amdgcn_mfma_f32_16x16x32_f16(a0, bv0, acc, 0, 0, 0);
        acc = __builtin_amdgcn_mfma_f32_16x16x32_f16(a1, bv1, acc, 0, 0, 0);
        // C: row = quad*4 + reg (edge), col = nrow
        __fp16* orow = rw + (size_t)(etile + quad*4) * 768 + nrow;
        orow[0]    = (__fp16)acc[0];
        orow[768]  = (__fp16)acc[1];
        orow[1536] = (__fp16)acc[2];
        orow[2304] = (__fp16)acc[3];
    }
}

// Kernel 2: per-edge conv + scores + v from precomputed rw (f16).
// t2pk fully in VGPRs (all constant indices); k rows via private LDS (stride 25).
__global__ __launch_bounds__(256)
void edge2_kernel(const int* __restrict__ src, const int* __restrict__ dst,
                  const float* __restrict__ basis, const float* __restrict__ f,
                  const __fp16* __restrict__ rw,
                  float* __restrict__ v_out, float* __restrict__ sc_out,
                  unsigned* __restrict__ smax, int ebase)
{
    __shared__ float lds[256 * 25];       // 25.6 KB
    float* my = lds + threadIdx.x * 25;

    const int el = blockIdx.x * blockDim.x + threadIdx.x;   // local
    const int e  = ebase + el;                               // global

    // ---- tmp2 packed f16 pairs (m'=2mp, 2mp+1), in REGISTERS ----
    half2_t t2pk[3][16];
    {
        float bas[18];
        const float2* bv = (const float2*)(basis + (size_t)e * 18);
        #pragma unroll
        for (int i = 0; i < 9; ++i) { float2 t = bv[i]; bas[2*i] = t.x; bas[2*i+1] = t.y; }
        float fe[48];
        const float4* fv = (const float4*)(f + (size_t)src[e] * 48);
        #pragma unroll
        for (int i = 0; i < 12; ++i) {
            float4 t = fv[i];
            fe[4*i+0] = t.x; fe[4*i+1] = t.y; fe[4*i+2] = t.z; fe[4*i+3] = t.w;
        }
        #pragma unroll
        for (int m = 0; m < 16; ++m) {
            #pragma unroll
            for (int d = 0; d < 3; ++d) {
                float v0 = fmaf(fe[m*3+0], bas[0*6 + d],
                           fmaf(fe[m*3+1], bas[1*6 + d],
                                fe[m*3+2] * bas[2*6 + d]));
                float v1 = fmaf(fe[m*3+0], bas[0*6 + 3 + d],
                           fmaf(fe[m*3+1], bas[1*6 + 3 + d],
                                fe[m*3+2] * bas[2*6 + 3 + d]));
                t2pk[d][m] = pk(v0, v1);
            }
        }
    }

    const uint4* __restrict__ rwrow = (const uint4*)(rw + (size_t)el * 768);
    const int dn = dst[e];

    #pragma unroll 1
    for (int c = 0; c < 24; ++c) {
        float a0 = 0.f, a1 = 0.f, a2 = 0.f;
        #pragma unroll
        for (int q = 0; q < 4; ++q) {
            uint4 w = rwrow[c*4 + q];
            a0 = fdot2(u2h(w.x), t2pk[0][q*4+0], a0);
            a1 = fdot2(u2h(w.x), t2pk[1][q*4+0], a1);
            a2 = fdot2(u2h(w.x), t2pk[2][q*4+0], a2);
            a0 = fdot2(u2h(w.y), t2pk[0][q*4+1], a0);
            a1 = fdot2(u2h(w.y), t2pk[1][q*4+1], a1);
            a2 = fdot2(u2h(w.y), t2pk[2][q*4+1], a2);
            a0 = fdot2(u2h(w.z), t2pk[0][q*4+2], a0);
            a1 = fdot2(u2h(w.z), t2pk[1][q*4+2], a1);
            a2 = fdot2(u2h(w.z), t2pk[2][q*4+2], a2);
            a0 = fdot2(u2h(w.w), t2pk[0][q*4+3], a0);
            a1 = fdot2(u2h(w.w), t2pk[1][q*4+3], a1);
            a2 = fdot2(u2h(w.w), t2pk[2][q*4+3], a2);
        }
        if (c < 8) {                       // k row
            my[c*3+0] = a0; my[c*3+1] = a1; my[c*3+2] = a2;
        } else if (c < 16) {               // q row -> score partial
            int hh = (c - 8) >> 1;
            float part = a0*my[(c-8)*3+0] + a1*my[(c-8)*3+1] + a2*my[(c-8)*3+2];
            if ((c & 1) == 0) my[24] = part;   // reuse slot: even row stores
            else {
                float s = (my[24] + part) * TEMP;
                s = (s > 0.0f) ? s : 0.2f * s;
                sc_out[e*4 + hh] = s;
                atomicMax(&smax[dn*4 + hh], enc_f32(s));
            }
        } else {                           // v row
            int o = e*24 + (c-16)*3;
            v_out[o+0] = a0; v_out[o+1] = a1; v_out[o+2] = a2;
        }
    }
}

// Kernel 3: ex = exp(score - smax[dst]) in-place, accumulate denom.
__global__ __launch_bounds__(256)
void exp_kernel(const int* __restrict__ dst, float* __restrict__ sc,
                const unsigned* __restrict__ smax, float* __restrict__ denom)
{
    int e = blockIdx.x * blockDim.x + threadIdx.x;
    int dn = dst[e];
    float4 s = *(const float4*)(sc + e*4);
    float e0 = __expf(s.x - dec_f32(smax[dn*4+0]));
    float e1 = __expf(s.y - dec_f32(smax[dn*4+1]));
    float e2 = __expf(s.z - dec_f32(smax[dn*4+2]));
    float e3 = __expf(s.w - dec_f32(smax[dn*4+3]));
    *(float4*)(sc + e*4) = make_float4(e0, e1, e2, e3);
    atomicAdd(&denom[dn*4+0], e0);
    atomicAdd(&denom[dn*4+1], e1);
    atomicAdd(&denom[dn*4+2], e2);
    atomicAdd(&denom[dn*4+3], e3);
}

// Kernel 4: one thread per (edge, component).
__global__ __launch_bounds__(256)
void scatter_kernel(const int* __restrict__ dst, const float* __restrict__ ex,
                    const float* __restrict__ v_in, float* __restrict__ out)
{
    int t = blockIdx.x * blockDim.x + threadIdx.x;  // t < E*24
    int e = t / 24;
    int j = t - e * 24;
    float w = ex[e*4 + j/6];
    atomicAdd(&out[dst[e]*24 + j], v_in[t] * w);
}

// Kernel 5: divide by denom (empty nodes -> 0).
__global__ __launch_bounds__(256)
void finalize_kernel(const float* __restrict__ denom, float* __restrict__ out)
{
    int i = blockIdx.x * blockDim.x + threadIdx.x;
    if (i >= N_NODES * 24) return;
    int n = i / 24;
    int hh = (i % 24) / 6;
    float dn = denom[n*4 + hh];
    float o = out[i];
    out[i] = (dn > 0.0f) ? (o / dn) : 0.0f;
}

extern "C" void kernel_launch(void* const* d_in, const int* in_sizes, int n_in,
                              void* d_out, int out_size, void* d_ws, size_t ws_size,
                              hipStream_t stream)
{
    const int*   src   = (const int*)d_in[0];
    const int*   dst   = (const int*)d_in[1];
    const float* basis = (const float*)d_in[2];
    const float* ef    = (const float*)d_in[3];
    const float* f     = (const float*)d_in[4];
    const float* W1    = (const float*)d_in[5];
    const float* b1    = (const float*)d_in[6];
    const float* W2    = (const float*)d_in[7];
    const float* b2    = (const float*)d_in[8];
    float* out = (float*)d_out;

    float*    v_buf  = (float*)d_ws;                              // E*24 f32
    float*    sc_buf = v_buf + (size_t)E_EDGES * 24;              // E*4 f32
    unsigned* smax   = (unsigned*)(sc_buf + (size_t)E_EDGES * 4); // N*4
    float*    denom  = (float*)(smax + (size_t)N_NODES * 4);      // N*4
    unsigned* w2h    = (unsigned*)(denom + (size_t)N_NODES * 4);  // 24576 dwords
    __fp16*   rw_buf = (__fp16*)(w2h + 24576);                    // chunk*768 f16

    // choose chunking so rw_buf fits ws_size (bytes so far: 18,338,304)
    size_t used = (size_t)(((char*)rw_buf) - (char*)d_ws);
    size_t avail = (ws_size > used) ? (ws_size - used) : 0;
    const size_t full = (size_t)E_EDGES * 768 * 2;
    int nc;
    if      (avail >= full)      nc = 1;
    else if (avail >= full/5)    nc = 5;
    else if (avail >= full/25)   nc = 25;
    else                         nc = 125;
    const int chunk = E_EDGES / nc;

    (void)hipMemsetAsync(smax, 0, (size_t)N_NODES * 4 * sizeof(unsigned), stream);
    (void)hipMemsetAsync(denom, 0, (size_t)N_NODES * 4 * sizeof(float), stream);
    (void)hipMemsetAsync(out, 0, (size_t)N_NODES * 24 * sizeof(float), stream);

    w2cvt_kernel<<<96, 256, 0, stream>>>(W2, w2h);

    for (int i = 0; i < nc; ++i) {
        const int base = i * chunk;
        gemm_kernel<<<chunk / 64, 256, 0, stream>>>(ef, W1, b1, (const __fp16*)w2h,
                                                    b2, rw_buf, base);
        edge2_kernel<<<chunk / 256, 256, 0, stream>>>(src, dst, basis, f, rw_buf,
                                                      v_buf, sc_buf, smax, base);
    }

    exp_kernel<<<E_EDGES / 256, 256, 0, stream>>>(dst, sc_buf, smax, denom);
    scatter_kernel<<<(E_EDGES * 24) / 256, 256, 0, stream>>>(dst, sc_buf, v_buf, out);
    int tot = N_NODES * 24;
    finalize_kernel<<<(tot + 255) / 256, 256, 0, stream>>>(denom, out);
}

// Round 8
// 323.933 us; speedup vs baseline: 1.3384x; 1.3384x over previous
//
#include <hip/hip_runtime.h>

#define E_EDGES 160000
#define N_NODES 10000

// 24^(-0.5)
#define TEMP 0.20412414523193154f

typedef __fp16 half2_t __attribute__((ext_vector_type(2)));
typedef __fp16 half8_t __attribute__((ext_vector_type(8)));
typedef float f32x4 __attribute__((ext_vector_type(4)));

__device__ __forceinline__ unsigned enc_f32(float x) {
    unsigned b = __float_as_uint(x);
    return b ^ ((b & 0x80000000u) ? 0xFFFFFFFFu : 0x80000000u);
}
__device__ __forceinline__ float dec_f32(unsigned k) {
    unsigned b = (k & 0x80000000u) ? (k ^ 0x80000000u) : ~k;
    return __uint_as_float(b);
}
__device__ __forceinline__ float fdot2(half2_t a, half2_t b, float c) {
#if __has_builtin(__builtin_amdgcn_fdot2)
    return __builtin_amdgcn_fdot2(a, b, c, false);
#else
    return fmaf((float)a.x, (float)b.x, fmaf((float)a.y, (float)b.y, c));
#endif
}

// W2 [768][64] f32 -> f16
__global__ __launch_bounds__(256)
void w2cvt_kernel(const float* __restrict__ W2, unsigned* __restrict__ w2h)
{
    int t = blockIdx.x * blockDim.x + threadIdx.x;   // t < 24576
    union { half2_t h; unsigned u; } c;
    c.h.x = (__fp16)W2[2*t]; c.h.y = (__fp16)W2[2*t+1];
    w2h[t] = c.u;
}

// ---- fused per-edge kernel: fp32 MLP + conv (MFMA + fdot2) + scores + v ----
// Per wave: 16 edges. rw never leaves the CU.

#define CONV_MFMA(c, A0, A1) { \
    const __fp16* p0_ = w2h + (size_t)((2*(c))*16 + em)*64 + quad*8; \
    const __fp16* p1_ = w2h + (size_t)((2*(c)+1)*16 + em)*64 + quad*8; \
    half8_t b00_ = *(const half8_t*)p0_; \
    half8_t b01_ = *(const half8_t*)(p0_ + 32); \
    half8_t b10_ = *(const half8_t*)p1_; \
    half8_t b11_ = *(const half8_t*)(p1_ + 32); \
    float bi0_ = b2[(2*(c))*16 + em], bi1_ = b2[(2*(c)+1)*16 + em]; \
    A0 = (f32x4){bi0_, bi0_, bi0_, bi0_}; \
    A0 = __builtin_amdgcn_mfma_f32_16x16x32_f16(a_lo, b00_, A0, 0, 0, 0); \
    A0 = __builtin_amdgcn_mfma_f32_16x16x32_f16(a_hi, b01_, A0, 0, 0, 0); \
    A1 = (f32x4){bi1_, bi1_, bi1_, bi1_}; \
    A1 = __builtin_amdgcn_mfma_f32_16x16x32_f16(a_lo, b10_, A1, 0, 0, 0); \
    A1 = __builtin_amdgcn_mfma_f32_16x16x32_f16(a_hi, b11_, A1, 0, 0, 0); }

#define CONV_WRITE(p, A0, A1) { \
    union { half2_t h[4]; uint4 u; } pk_; \
    pk_.h[0].x = (__fp16)A0[0]; pk_.h[0].y = (__fp16)A1[0]; \
    pk_.h[1].x = (__fp16)A0[1]; pk_.h[1].y = (__fp16)A1[1]; \
    pk_.h[2].x = (__fp16)A0[2]; pk_.h[2].y = (__fp16)A1[2]; \
    pk_.h[3].x = (__fp16)A0[3]; pk_.h[3].y = (__fp16)A1[3]; \
    *(uint4*)&rw2t[wid][p][em][quad*4] = pk_.u; }

#define CONV_DOT(c, p) { \
    half2_t rv0_ = rw2t[wid][p][quad*4+0][em]; \
    half2_t rv1_ = rw2t[wid][p][quad*4+1][em]; \
    half2_t rv2_ = rw2t[wid][p][quad*4+2][em]; \
    half2_t rv3_ = rw2t[wid][p][quad*4+3][em]; \
    float p0_=0.f, p1_=0.f, p2_=0.f; \
    p0_=fdot2(rv0_,t2[0][0],p0_); p1_=fdot2(rv0_,t2[0][1],p1_); p2_=fdot2(rv0_,t2[0][2],p2_); \
    p0_=fdot2(rv1_,t2[1][0],p0_); p1_=fdot2(rv1_,t2[1][1],p1_); p2_=fdot2(rv1_,t2[1][2],p2_); \
    p0_=fdot2(rv2_,t2[2][0],p0_); p1_=fdot2(rv2_,t2[2][1],p1_); p2_=fdot2(rv2_,t2[2][2],p2_); \
    p0_=fdot2(rv3_,t2[3][0],p0_); p1_=fdot2(rv3_,t2[3][1],p1_); p2_=fdot2(rv3_,t2[3][2],p2_); \
    p0_ += __shfl_xor(p0_, 16); p0_ += __shfl_xor(p0_, 32); \
    p1_ += __shfl_xor(p1_, 16); p1_ += __shfl_xor(p1_, 32); \
    p2_ += __shfl_xor(p2_, 16); p2_ += __shfl_xor(p2_, 32); \
    if ((c) < 8)       { kreg[(c)&7][0]=p0_; kreg[(c)&7][1]=p1_; kreg[(c)&7][2]=p2_; } \
    else if ((c) < 16) { float s_ = p0_*kreg[(c)&7][0] + p1_*kreg[(c)&7][1] + p2_*kreg[(c)&7][2]; \
                         if (((c)&1)==0) sreg[((c)&7)>>1] = s_; else sreg[((c)&7)>>1] += s_; } \
    else               { vreg[(c)&7][0]=p0_; vreg[(c)&7][1]=p1_; vreg[(c)&7][2]=p2_; } }

__global__ __launch_bounds__(256)
void fused_kernel(const int* __restrict__ src, const int* __restrict__ dst,
                  const float* __restrict__ basis, const float* __restrict__ efeat,
                  const float* __restrict__ f,
                  const float* __restrict__ W1, const float* __restrict__ b1,
                  const __fp16* __restrict__ w2h, const float* __restrict__ b2,
                  float* __restrict__ v_out, float* __restrict__ sc_out,
                  unsigned* __restrict__ smax)
{
    __shared__ __fp16  h_tile[4][16][72];        // [wid][e][k], 9216 B
    __shared__ half2_t rw2t[4][2][16][20];       // [wid][parity][mp][e + pad], 10240 B

    const int lane = threadIdx.x & 63;
    const int wid  = threadIdx.x >> 6;
    const int em   = lane & 15;
    const int quad = lane >> 4;
    const int etile = (blockIdx.x * 4 + wid) * 16;
    const int e = etile + em;     // this lane's edge (4 quad-lanes per edge)

    // ---- Phase A: h = relu(x @ W1^T + b1) in fp32 (R6-validated numerics) ----
    // lane (em, quad) computes h[edge=etile+em][j = quad*16 .. +16), f16 to LDS
    {
        float x[32];
        const float4* xv = (const float4*)(efeat + (size_t)e * 32);
        #pragma unroll
        for (int i = 0; i < 8; ++i) {
            float4 t = xv[i];
            x[4*i+0] = t.x; x[4*i+1] = t.y; x[4*i+2] = t.z; x[4*i+3] = t.w;
        }
        const int jg = quad * 16;
        half8_t hv0, hv1;
        #pragma unroll
        for (int t = 0; t < 16; ++t) {
            const int j = jg + t;
            float a = b1[j];
            const float* __restrict__ w = W1 + j*32;
            #pragma unroll
            for (int i = 0; i < 32; ++i) a = fmaf(w[i], x[i], a);
            a = fmaxf(a, 0.0f);
            if (t < 8) hv0[t] = (__fp16)a; else hv1[t-8] = (__fp16)a;
        }
        *(half8_t*)&h_tile[wid][em][jg]     = hv0;
        *(half8_t*)&h_tile[wid][em][jg + 8] = hv1;
    }
    __syncthreads();
    half8_t a_lo = *(const half8_t*)&h_tile[wid][em][quad*8];
    half8_t a_hi = *(const half8_t*)&h_tile[wid][em][32 + quad*8];

    // ---- Phase B: tmp2 quarter (mp = quad*4..+4), pairs (m', m'+16), in regs ----
    half2_t t2[4][3];
    {
        float bas[18];
        const float2* bv = (const float2*)(basis + (size_t)e * 18);
        #pragma unroll
        for (int i = 0; i < 9; ++i) { float2 t = bv[i]; bas[2*i] = t.x; bas[2*i+1] = t.y; }
        const float* fp = f + (size_t)src[e] * 48 + quad*6;
        float fl[6], fh[6];
        #pragma unroll
        for (int i = 0; i < 3; ++i) {
            float2 a = *(const float2*)(fp + 2*i);      fl[2*i] = a.x; fl[2*i+1] = a.y;
            float2 b = *(const float2*)(fp + 24 + 2*i); fh[2*i] = b.x; fh[2*i+1] = b.y;
        }
        #pragma unroll
        for (int jj = 0; jj < 4; ++jj) {
            const int mr = (jj >> 1) * 3;
            const int rb = (jj & 1) * 3;
            #pragma unroll
            for (int d = 0; d < 3; ++d) {
                float lo = fmaf(fl[mr+0], bas[rb+d],
                           fmaf(fl[mr+1], bas[6+rb+d], fl[mr+2] * bas[12+rb+d]));
                float hi = fmaf(fh[mr+0], bas[rb+d],
                           fmaf(fh[mr+1], bas[6+rb+d], fh[mr+2] * bas[12+rb+d]));
                half2_t v; v.x = (__fp16)lo; v.y = (__fp16)hi;
                t2[jj][d] = v;
            }
        }
    }

    // ---- Phase C: 24 conv rows, pair-wise double-buffered through LDS ----
    float kreg[8][3], vreg[8][3], sreg[4];
    #pragma unroll
    for (int t = 0; t < 12; ++t) {
        { f32x4 A0, A1; CONV_MFMA(2*t,   A0, A1); CONV_WRITE(0, A0, A1); }
        { f32x4 A0, A1; CONV_MFMA(2*t+1, A0, A1); CONV_WRITE(1, A0, A1); }
        __syncthreads();
        CONV_DOT(2*t,   0);
        CONV_DOT(2*t+1, 1);
        __syncthreads();
    }

    // ---- Epilogue ----
    #pragma unroll
    for (int hh = 0; hh < 4; ++hh) {
        float s = sreg[hh] * TEMP;
        sreg[hh] = (s > 0.0f) ? s : 0.2f * s;
    }
    const int dn = dst[e];
    atomicMax(&smax[dn*4 + quad], enc_f32(sreg[quad]));
    float* vb = v_out + (size_t)e * 24;
    if (quad == 3) {
        *(float4*)(sc_out + (size_t)e*4) = make_float4(sreg[0], sreg[1], sreg[2], sreg[3]);
    } else if (quad == 0) {
        *(float4*)(vb+0) = make_float4(vreg[0][0], vreg[0][1], vreg[0][2], vreg[1][0]);
        *(float4*)(vb+4) = make_float4(vreg[1][1], vreg[1][2], vreg[2][0], vreg[2][1]);
    } else if (quad == 1) {
        *(float4*)(vb+8)  = make_float4(vreg[2][2], vreg[3][0], vreg[3][1], vreg[3][2]);
        *(float4*)(vb+12) = make_float4(vreg[4][0], vreg[4][1], vreg[4][2], vreg[5][0]);
    } else {
        *(float4*)(vb+16) = make_float4(vreg[5][1], vreg[5][2], vreg[6][0], vreg[6][1]);
        *(float4*)(vb+20) = make_float4(vreg[6][2], vreg[7][0], vreg[7][1], vreg[7][2]);
    }
}

// ex = exp(score - smax[dst]) in-place, accumulate denom.
__global__ __launch_bounds__(256)
void exp_kernel(const int* __restrict__ dst, float* __restrict__ sc,
                const unsigned* __restrict__ smax, float* __restrict__ denom)
{
    int e = blockIdx.x * blockDim.x + threadIdx.x;
    int dn = dst[e];
    float4 s = *(const float4*)(sc + e*4);
    float e0 = __expf(s.x - dec_f32(smax[dn*4+0]));
    float e1 = __expf(s.y - dec_f32(smax[dn*4+1]));
    float e2 = __expf(s.z - dec_f32(smax[dn*4+2]));
    float e3 = __expf(s.w - dec_f32(smax[dn*4+3]));
    *(float4*)(sc + e*4) = make_float4(e0, e1, e2, e3);
    atomicAdd(&denom[dn*4+0], e0);
    atomicAdd(&denom[dn*4+1], e1);
    atomicAdd(&denom[dn*4+2], e2);
    atomicAdd(&denom[dn*4+3], e3);
}

// one thread per (edge, component)
__global__ __launch_bounds__(256)
void scatter_kernel(const int* __restrict__ dst, const float* __restrict__ ex,
                    const float* __restrict__ v_in, float* __restrict__ out)
{
    int t = blockIdx.x * blockDim.x + threadIdx.x;  // t < E*24
    int e = t / 24;
    int j = t - e * 24;
    float w = ex[e*4 + j/6];
    atomicAdd(&out[dst[e]*24 + j], v_in[t] * w);
}

__global__ __launch_bounds__(256)
void finalize_kernel(const float* __restrict__ denom, float* __restrict__ out)
{
    int i = blockIdx.x * blockDim.x + threadIdx.x;
    if (i >= N_NODES * 24) return;
    int n = i / 24;
    int hh = (i % 24) / 6;
    float dn = denom[n*4 + hh];
    float o = out[i];
    out[i] = (dn > 0.0f) ? (o / dn) : 0.0f;
}

extern "C" void kernel_launch(void* const* d_in, const int* in_sizes, int n_in,
                              void* d_out, int out_size, void* d_ws, size_t ws_size,
                              hipStream_t stream)
{
    const int*   src   = (const int*)d_in[0];
    const int*   dst   = (const int*)d_in[1];
    const float* basis = (const float*)d_in[2];
    const float* ef    = (const float*)d_in[3];
    const float* f     = (const float*)d_in[4];
    const float* W1    = (const float*)d_in[5];
    const float* b1    = (const float*)d_in[6];
    const float* W2    = (const float*)d_in[7];
    const float* b2    = (const float*)d_in[8];
    float* out = (float*)d_out;

    float*    v_buf  = (float*)d_ws;                              // E*24 f32
    float*    sc_buf = v_buf + (size_t)E_EDGES * 24;              // E*4 f32
    unsigned* smax   = (unsigned*)(sc_buf + (size_t)E_EDGES * 4); // N*4
    float*    denom  = (float*)(smax + (size_t)N_NODES * 4);      // N*4
    unsigned* w2h    = (unsigned*)(denom + (size_t)N_NODES * 4);  // 24576 u32

    (void)hipMemsetAsync(smax, 0, (size_t)N_NODES * 4 * sizeof(unsigned), stream);
    (void)hipMemsetAsync(denom, 0, (size_t)N_NODES * 4 * sizeof(float), stream);
    (void)hipMemsetAsync(out, 0, (size_t)N_NODES * 24 * sizeof(float), stream);

    w2cvt_kernel<<<96, 256, 0, stream>>>(W2, w2h);

    fused_kernel<<<E_EDGES / 64, 256, 0, stream>>>(src, dst, basis, ef, f,
                                                   W1, b1, (const __fp16*)w2h, b2,
                                                   v_buf, sc_buf, smax);

    exp_kernel<<<E_EDGES / 256, 256, 0, stream>>>(dst, sc_buf, smax, denom);
    scatter_kernel<<<(E_EDGES * 24) / 256, 256, 0, stream>>>(dst, sc_buf, v_buf, out);
    int tot = N_NODES * 24;
    finalize_kernel<<<(tot + 255) / 256, 256, 0, stream>>>(denom, out);
}

// Round 9
// 322.465 us; speedup vs baseline: 1.3445x; 1.0046x over previous
//
#include <hip/hip_runtime.h>

#define E_EDGES 160000
#define N_NODES 10000

// 24^(-0.5)
#define TEMP 0.20412414523193154f

typedef __fp16 half2_t __attribute__((ext_vector_type(2)));
typedef __fp16 half8_t __attribute__((ext_vector_type(8)));
typedef float f32x4 __attribute__((ext_vector_type(4)));

__device__ __forceinline__ unsigned enc_f32(float x) {
    unsigned b = __float_as_uint(x);
    return b ^ ((b & 0x80000000u) ? 0xFFFFFFFFu : 0x80000000u);
}
__device__ __forceinline__ float dec_f32(unsigned k) {
    unsigned b = (k & 0x80000000u) ? (k ^ 0x80000000u) : ~k;
    return __uint_as_float(b);
}
__device__ __forceinline__ float fdot2(half2_t a, half2_t b, float c) {
#if __has_builtin(__builtin_amdgcn_fdot2)
    return __builtin_amdgcn_fdot2(a, b, c, false);
#else
    return fmaf((float)a.x, (float)b.x, fmaf((float)a.y, (float)b.y, c));
#endif
}
__device__ __forceinline__ half2_t pk(float a, float b) {
    return __builtin_amdgcn_cvt_pkrtz(a, b);
}

// W2 [768][64] f32 -> f16
__global__ __launch_bounds__(256)
void w2cvt_kernel(const float* __restrict__ W2, unsigned* __restrict__ w2h)
{
    int t = blockIdx.x * blockDim.x + threadIdx.x;   // t < 24576
    union { half2_t h; unsigned u; } c;
    c.h.x = (__fp16)W2[2*t]; c.h.y = (__fp16)W2[2*t+1];
    w2h[t] = c.u;
}

// ---- fused per-edge kernel: fp32 MLP + conv via MFMA(A=W2, B=h) + fdot2 ----
// Per wave: 16 edges. NO LDS, NO barriers: D-layout (row=m', col=edge) lands
// rw pairs exactly on the lane that holds the matching t2 quarter.
__global__ __launch_bounds__(256, 2)
void fused_kernel(const int* __restrict__ src, const int* __restrict__ dst,
                  const float* __restrict__ basis, const float* __restrict__ efeat,
                  const float* __restrict__ f,
                  const float* __restrict__ W1, const float* __restrict__ b1,
                  const __fp16* __restrict__ w2h, const float* __restrict__ b2,
                  float* __restrict__ v_out, float* __restrict__ sc_out,
                  unsigned* __restrict__ smax)
{
    const int lane = threadIdx.x & 63;
    const int wid  = threadIdx.x >> 6;
    const int em   = lane & 15;
    const int quad = lane >> 4;
    const int e = (blockIdx.x * 4 + wid) * 16 + em;   // this lane's edge

    // ---- Phase A: h = relu(x @ W1^T + b1), fp32 math; each lane computes exactly
    // its B-fragment j-sets: j in [quad*8, quad*8+8) and [32+quad*8, 32+quad*8+8)
    half8_t h_lo, h_hi;
    {
        float x[32];
        const float4* xv = (const float4*)(efeat + (size_t)e * 32);
        #pragma unroll
        for (int i = 0; i < 8; ++i) {
            float4 t = xv[i];
            x[4*i+0] = t.x; x[4*i+1] = t.y; x[4*i+2] = t.z; x[4*i+3] = t.w;
        }
        union { __fp16 h[8]; half8_t v; } lo, hi;
        #pragma unroll
        for (int t = 0; t < 8; ++t) {
            const int j0 = quad*8 + t;
            const int j1 = 32 + quad*8 + t;
            float a0 = b1[j0], a1 = b1[j1];
            const float* __restrict__ w0 = W1 + j0*32;
            const float* __restrict__ w1 = W1 + j1*32;
            #pragma unroll
            for (int i = 0; i < 32; ++i) {
                a0 = fmaf(w0[i], x[i], a0);
                a1 = fmaf(w1[i], x[i], a1);
            }
            lo.h[t] = (__fp16)fmaxf(a0, 0.0f);
            hi.h[t] = (__fp16)fmaxf(a1, 0.0f);
        }
        h_lo = lo.v; h_hi = hi.v;
    }

    // ---- Phase B: tmp2 quarter (mp = quad*4..+4), pairs (m', m'+16), in regs ----
    half2_t t2[4][3];
    {
        float bas[18];
        const float2* bv = (const float2*)(basis + (size_t)e * 18);
        #pragma unroll
        for (int i = 0; i < 9; ++i) { float2 t = bv[i]; bas[2*i] = t.x; bas[2*i+1] = t.y; }
        const float* fp = f + (size_t)src[e] * 48 + quad*6;
        float fl[6], fh[6];
        #pragma unroll
        for (int i = 0; i < 3; ++i) {
            float2 a = *(const float2*)(fp + 2*i);      fl[2*i] = a.x; fl[2*i+1] = a.y;
            float2 b = *(const float2*)(fp + 24 + 2*i); fh[2*i] = b.x; fh[2*i+1] = b.y;
        }
        #pragma unroll
        for (int jj = 0; jj < 4; ++jj) {
            const int mr = (jj >> 1) * 3;
            const int rb = (jj & 1) * 3;
            #pragma unroll
            for (int d = 0; d < 3; ++d) {
                float lo = fmaf(fl[mr+0], bas[rb+d],
                           fmaf(fl[mr+1], bas[6+rb+d], fl[mr+2] * bas[12+rb+d]));
                float hi = fmaf(fh[mr+0], bas[rb+d],
                           fmaf(fh[mr+1], bas[6+rb+d], fh[mr+2] * bas[12+rb+d]));
                t2[jj][d] = pk(lo, hi);
            }
        }
    }

    // ---- Phase C: 24 conv rows. A = W2 block rows (m' dim), B = h (edge dim).
    // D: row(=quad*4+r) = m', col(=em) = edge -> no transpose needed.
    float kreg[8][3], vreg[8][3], sreg[4];
    #pragma unroll
    for (int c = 0; c < 24; ++c) {
        // A-frags: W2 rows [32c+em] (m'-half 0) and [32c+16+em] (m'-half 1)
        const __fp16* pa = w2h + (size_t)(32*c + em)*64 + quad*8;
        half8_t wa0 = *(const half8_t*)pa;            // k = quad*8..+8
        half8_t wa1 = *(const half8_t*)(pa + 32);     // k = 32+quad*8..+8
        const __fp16* pb = pa + 16*64;
        half8_t wb0 = *(const half8_t*)pb;
        half8_t wb1 = *(const half8_t*)(pb + 32);
        float4 bb0 = *(const float4*)(b2 + 32*c + quad*4);
        float4 bb1 = *(const float4*)(b2 + 32*c + 16 + quad*4);

        f32x4 acc0 = {bb0.x, bb0.y, bb0.z, bb0.w};
        acc0 = __builtin_amdgcn_mfma_f32_16x16x32_f16(wa0, h_lo, acc0, 0, 0, 0);
        acc0 = __builtin_amdgcn_mfma_f32_16x16x32_f16(wa1, h_hi, acc0, 0, 0, 0);
        f32x4 acc1 = {bb1.x, bb1.y, bb1.z, bb1.w};
        acc1 = __builtin_amdgcn_mfma_f32_16x16x32_f16(wb0, h_lo, acc1, 0, 0, 0);
        acc1 = __builtin_amdgcn_mfma_f32_16x16x32_f16(wb1, h_hi, acc1, 0, 0, 0);

        float p0 = 0.f, p1 = 0.f, p2 = 0.f;
        #pragma unroll
        for (int r = 0; r < 4; ++r) {
            half2_t rp = pk(acc0[r], acc1[r]);        // (m'=q4+r, m'=16+q4+r)
            p0 = fdot2(rp, t2[r][0], p0);
            p1 = fdot2(rp, t2[r][1], p1);
            p2 = fdot2(rp, t2[r][2], p2);
        }
        p0 += __shfl_xor(p0, 16); p0 += __shfl_xor(p0, 32);
        p1 += __shfl_xor(p1, 16); p1 += __shfl_xor(p1, 32);
        p2 += __shfl_xor(p2, 16); p2 += __shfl_xor(p2, 32);

        if (c < 8)       { kreg[c][0]=p0; kreg[c][1]=p1; kreg[c][2]=p2; }
        else if (c < 16) {
            float s_ = p0*kreg[c-8][0] + p1*kreg[c-8][1] + p2*kreg[c-8][2];
            if (((c)&1)==0) sreg[(c-8)>>1] = s_; else sreg[(c-8)>>1] += s_;
        }
        else             { vreg[c-16][0]=p0; vreg[c-16][1]=p1; vreg[c-16][2]=p2; }
    }

    // ---- Epilogue ----
    #pragma unroll
    for (int hh = 0; hh < 4; ++hh) {
        float s = sreg[hh] * TEMP;
        sreg[hh] = (s > 0.0f) ? s : 0.2f * s;
    }
    const int dn = dst[e];
    atomicMax(&smax[dn*4 + quad], enc_f32(sreg[quad]));
    float* vb = v_out + (size_t)e * 24;
    if (quad == 3) {
        *(float4*)(sc_out + (size_t)e*4) = make_float4(sreg[0], sreg[1], sreg[2], sreg[3]);
    } else if (quad == 0) {
        *(float4*)(vb+0) = make_float4(vreg[0][0], vreg[0][1], vreg[0][2], vreg[1][0]);
        *(float4*)(vb+4) = make_float4(vreg[1][1], vreg[1][2], vreg[2][0], vreg[2][1]);
    } else if (quad == 1) {
        *(float4*)(vb+8)  = make_float4(vreg[2][2], vreg[3][0], vreg[3][1], vreg[3][2]);
        *(float4*)(vb+12) = make_float4(vreg[4][0], vreg[4][1], vreg[4][2], vreg[5][0]);
    } else {
        *(float4*)(vb+16) = make_float4(vreg[5][1], vreg[5][2], vreg[6][0], vreg[6][1]);
        *(float4*)(vb+20) = make_float4(vreg[6][2], vreg[7][0], vreg[7][1], vreg[7][2]);
    }
}

// ex = exp(score - smax[dst]) in-place, accumulate denom.
__global__ __launch_bounds__(256)
void exp_kernel(const int* __restrict__ dst, float* __restrict__ sc,
                const unsigned* __restrict__ smax, float* __restrict__ denom)
{
    int e = blockIdx.x * blockDim.x + threadIdx.x;
    int dn = dst[e];
    float4 s = *(const float4*)(sc + e*4);
    float e0 = __expf(s.x - dec_f32(smax[dn*4+0]));
    float e1 = __expf(s.y - dec_f32(smax[dn*4+1]));
    float e2 = __expf(s.z - dec_f32(smax[dn*4+2]));
    float e3 = __expf(s.w - dec_f32(smax[dn*4+3]));
    *(float4*)(sc + e*4) = make_float4(e0, e1, e2, e3);
    atomicAdd(&denom[dn*4+0], e0);
    atomicAdd(&denom[dn*4+1], e1);
    atomicAdd(&denom[dn*4+2], e2);
    atomicAdd(&denom[dn*4+3], e3);
}

// one thread per (edge, component)
__global__ __launch_bounds__(256)
void scatter_kernel(const int* __restrict__ dst, const float* __restrict__ ex,
                    const float* __restrict__ v_in, float* __restrict__ out)
{
    int t = blockIdx.x * blockDim.x + threadIdx.x;  // t < E*24
    int e = t / 24;
    int j = t - e * 24;
    float w = ex[e*4 + j/6];
    atomicAdd(&out[dst[e]*24 + j], v_in[t] * w);
}

__global__ __launch_bounds__(256)
void finalize_kernel(const float* __restrict__ denom, float* __restrict__ out)
{
    int i = blockIdx.x * blockDim.x + threadIdx.x;
    if (i >= N_NODES * 24) return;
    int n = i / 24;
    int hh = (i % 24) / 6;
    float dn = denom[n*4 + hh];
    float o = out[i];
    out[i] = (dn > 0.0f) ? (o / dn) : 0.0f;
}

extern "C" void kernel_launch(void* const* d_in, const int* in_sizes, int n_in,
                              void* d_out, int out_size, void* d_ws, size_t ws_size,
                              hipStream_t stream)
{
    const int*   src   = (const int*)d_in[0];
    const int*   dst   = (const int*)d_in[1];
    const float* basis = (const float*)d_in[2];
    const float* ef    = (const float*)d_in[3];
    const float* f     = (const float*)d_in[4];
    const float* W1    = (const float*)d_in[5];
    const float* b1    = (const float*)d_in[6];
    const float* W2    = (const float*)d_in[7];
    const float* b2    = (const float*)d_in[8];
    float* out = (float*)d_out;

    float*    v_buf  = (float*)d_ws;                              // E*24 f32
    float*    sc_buf = v_buf + (size_t)E_EDGES * 24;              // E*4 f32
    unsigned* smax   = (unsigned*)(sc_buf + (size_t)E_EDGES * 4); // N*4
    float*    denom  = (float*)(smax + (size_t)N_NODES * 4);      // N*4
    unsigned* w2h    = (unsigned*)(denom + (size_t)N_NODES * 4);  // 24576 u32

    (void)hipMemsetAsync(smax, 0, (size_t)N_NODES * 4 * sizeof(unsigned), stream);
    (void)hipMemsetAsync(denom, 0, (size_t)N_NODES * 4 * sizeof(float), stream);
    (void)hipMemsetAsync(out, 0, (size_t)N_NODES * 24 * sizeof(float), stream);

    w2cvt_kernel<<<96, 256, 0, stream>>>(W2, w2h);

    fused_kernel<<<E_EDGES / 64, 256, 0, stream>>>(src, dst, basis, ef, f,
                                                   W1, b1, (const __fp16*)w2h, b2,
                                                   v_buf, sc_buf, smax);

    exp_kernel<<<E_EDGES / 256, 256, 0, stream>>>(dst, sc_buf, smax, denom);
    scatter_kernel<<<(E_EDGES * 24) / 256, 256, 0, stream>>>(dst, sc_buf, v_buf, out);
    int tot = N_NODES * 24;
    finalize_kernel<<<(tot + 255) / 256, 256, 0, stream>>>(denom, out);
}